// Round 2
// baseline (5989.498 us; speedup 1.0000x reference)
//
#include <hip/hip_runtime.h>
#include <math.h>

#define HIDC 128
#define EDGEF 16
#define LAY 3
#define KNN 3
#define UU 4
#define NBLK 20000
#define NATOM (NBLK*UU)      // 80000
#define EBK 30000
#define EALL (EBK*UU*KNN)    // 360000

__device__ __forceinline__ float silu_f(float v) {
    return v / (1.0f + expf(-v));
}

// ---------------- degree histogram (for cnt) ----------------

__global__ void k_count(const int* __restrict__ edges, int* __restrict__ degB) {
    int e = blockIdx.x * 256 + threadIdx.x;
    if (e < EBK) atomicAdd(&degB[edges[e]], 1);
}

// top-3 nearest dst atoms per src atom; exact f32 arithmetic (no fma contraction)
__global__ void k_topk(const int* __restrict__ edges, const float* __restrict__ Z,
                       int* __restrict__ colIdx) {
    int t = blockIdx.x * 256 + threadIdx.x;
    if (t >= EBK * UU) return;
    int e = t >> 2, u = t & 3;
    int b0 = edges[e], b1 = edges[EBK + e];
    int s = b0 * UU + u;
    float zs0 = Z[s*3+0], zs1 = Z[s*3+1], zs2 = Z[s*3+2];
    float d2[UU];
    #pragma unroll
    for (int v = 0; v < UU; v++) {
        int d = b1 * UU + v;
        float a0 = __fsub_rn(zs0, Z[d*3+0]);
        float a1 = __fsub_rn(zs1, Z[d*3+1]);
        float a2 = __fsub_rn(zs2, Z[d*3+2]);
        float p0 = __fmul_rn(a0, a0);
        float p1 = __fmul_rn(a1, a1);
        float p2 = __fmul_rn(a2, a2);
        d2[v] = __fadd_rn(__fadd_rn(p0, p1), p2);
    }
    bool used[UU] = {false, false, false, false};
    #pragma unroll
    for (int k = 0; k < KNN; k++) {
        int best = -1;
        float bd = INFINITY;
        #pragma unroll
        for (int v = 0; v < UU; v++) {
            if (!used[v] && d2[v] < bd) { bd = d2[v]; best = v; }
        }
        used[best] = true;
        colIdx[t * KNN + k] = b1 * UU + best;
    }
}

// ---------------- generic tiled f32 GEMM (node / emb MLPs) ----------------
// C[M x 128] = act( A[M x KT] @ W[KT x 128] + bias ) (+ R). In-place-safe
// per-block (each block stages its own 32 A-rows before writing them).

template<int KT, bool DOSILU, bool DORES, bool SPLIT>
__global__ __launch_bounds__(128) void k_gemm(
    const float* __restrict__ A0, const float* __restrict__ A1,
    const float* __restrict__ W, const float* __restrict__ bias,
    const float* __restrict__ R, float* __restrict__ C, int M)
{
    __shared__ float At[KT][32];
    __shared__ float Bs[32][128];
    const int tid = threadIdx.x;
    const int tile0 = blockIdx.x * 32;
    const int r = tid >> 2, part = tid & 3;
    const int gr = tile0 + r;

    if (gr < M) {
        const float* a0r = A0 + (size_t)gr * 128;
        #pragma unroll
        for (int j = 0; j < 8; j++) {
            int c = part * 32 + j * 4;
            float4 v = *(const float4*)(a0r + c);
            At[c][r] = v.x; At[c+1][r] = v.y; At[c+2][r] = v.z; At[c+3][r] = v.w;
        }
        if (SPLIT) {
            const float* a1r = A1 + (size_t)gr * 128;
            #pragma unroll
            for (int j = 0; j < 8; j++) {
                int c = part * 32 + j * 4;
                float4 v = *(const float4*)(a1r + c);
                At[128+c][r] = v.x; At[129+c][r] = v.y; At[130+c][r] = v.z; At[131+c][r] = v.w;
            }
        }
    } else {
        #pragma unroll
        for (int j = 0; j < 8; j++) {
            int c = part * 32 + j * 4;
            At[c][r] = 0.f; At[c+1][r] = 0.f; At[c+2][r] = 0.f; At[c+3][r] = 0.f;
            if (SPLIT) { At[128+c][r] = 0.f; At[129+c][r] = 0.f; At[130+c][r] = 0.f; At[131+c][r] = 0.f; }
        }
    }

    float acc[4][8];
    #pragma unroll
    for (int i = 0; i < 4; i++)
        #pragma unroll
        for (int j = 0; j < 8; j++) acc[i][j] = 0.f;

    const int tx = tid & 15, ty = tid >> 4;

    for (int kb = 0; kb < KT / 32; kb++) {
        __syncthreads();
        #pragma unroll
        for (int j = 0; j < 8; j++) {
            int li = j * 512 + tid * 4;
            int kk = li >> 7, c = li & 127;
            float4 v = *(const float4*)(W + (size_t)(kb * 32 + kk) * 128 + c);
            *(float4*)&Bs[kk][c] = v;
        }
        __syncthreads();
        #pragma unroll 8
        for (int kk = 0; kk < 32; kk++) {
            float4 a  = *(const float4*)&At[kb * 32 + kk][ty * 4];
            float4 b0 = *(const float4*)&Bs[kk][tx * 8];
            float4 b1 = *(const float4*)&Bs[kk][tx * 8 + 4];
            float av[4] = {a.x, a.y, a.z, a.w};
            float bv[8] = {b0.x, b0.y, b0.z, b0.w, b1.x, b1.y, b1.z, b1.w};
            #pragma unroll
            for (int i = 0; i < 4; i++)
                #pragma unroll
                for (int j = 0; j < 8; j++)
                    acc[i][j] = fmaf(av[i], bv[j], acc[i][j]);
        }
    }

    #pragma unroll
    for (int i = 0; i < 4; i++) {
        int grr = tile0 + ty * 4 + i;
        if (grr >= M) continue;
        #pragma unroll
        for (int j = 0; j < 8; j++) {
            int c = tx * 8 + j;
            float v = acc[i][j] + bias[c];
            if (DOSILU) v = silu_f(v);
            if (DORES)  v += R[(size_t)grr * 128 + c];
            C[(size_t)grr * 128 + c] = v;
        }
    }
}

// ---------------- fused edge pipeline (one layer) ----------------
// Per 32-edge tile: gather -> edge MLP (273->128->128) -> coord MLP (->1)
// -> atomic scatter into agg[N,128] and xacc[N,3]. No m materialization.

__global__ __launch_bounds__(128) void k_edge_fused(
    const float* __restrict__ h, const float* __restrict__ x,
    const float* __restrict__ eattr, const int* __restrict__ edges0,
    const int* __restrict__ colIdx,
    const float* __restrict__ ew1, const float* __restrict__ eb1,
    const float* __restrict__ ew2, const float* __restrict__ eb2,
    const float* __restrict__ cw1, const float* __restrict__ cb1,
    const float* __restrict__ cw2,
    float* __restrict__ agg, float* __restrict__ xacc)
{
    __shared__ float At[288][32];   // phase1 A; [0:128) reused as m1^T; [128:256) as m^T
    __shared__ float Bs[32][128];
    __shared__ float red[32][17];
    __shared__ int   rowS[32];
    __shared__ float diffS[32][3];

    const int tid = threadIdx.x;
    const int tile0 = blockIdx.x * 32;
    const int r = tid >> 2, part = tid & 3;
    const int idx = tile0 + r;          // EALL % 32 == 0, always valid

    // ---- stage gathered A ----
    {
        const int e = idx / 12;
        const int u = (idx / 3) & 3;
        const int row = edges0[e] * 4 + u;
        const int col = colIdx[idx];
        const float* hr = h + (size_t)row * 128;
        const float* hc = h + (size_t)col * 128;
        #pragma unroll
        for (int j = 0; j < 8; j++) {
            int c = part * 32 + j * 4;
            float4 a = *(const float4*)(hr + c);
            At[c][r] = a.x; At[c+1][r] = a.y; At[c+2][r] = a.z; At[c+3][r] = a.w;
            float4 b = *(const float4*)(hc + c);
            At[128+c][r] = b.x; At[129+c][r] = b.y; At[130+c][r] = b.z; At[131+c][r] = b.w;
        }
        if (part == 0) {
            float dx = x[row*3+0] - x[col*3+0];
            float dy = x[row*3+1] - x[col*3+1];
            float dz = x[row*3+2] - x[col*3+2];
            At[256][r] = dx*dx + dy*dy + dz*dz;
            diffS[r][0] = dx; diffS[r][1] = dy; diffS[r][2] = dz;
            rowS[r] = row;
        } else if (part == 1) {
            const float* ea = eattr + (size_t)e * EDGEF;
            #pragma unroll
            for (int q = 0; q < EDGEF; q++) At[257+q][r] = ea[q];
        } else if (part == 2) {
            #pragma unroll
            for (int q = 273; q < 288; q++) At[q][r] = 0.f;
        }
    }

    const int tx = tid & 15, ty = tid >> 4;
    float acc[4][8];

    // ---- phase 1: m1 = silu(concat @ ew1 + eb1), K=288 (273 valid) ----
    #pragma unroll
    for (int i = 0; i < 4; i++)
        #pragma unroll
        for (int j = 0; j < 8; j++) acc[i][j] = 0.f;

    for (int kb = 0; kb < 9; kb++) {
        __syncthreads();
        #pragma unroll
        for (int j = 0; j < 8; j++) {
            int li = j * 512 + tid * 4;
            int kk = li >> 7, c = li & 127;
            int kg = kb * 32 + kk;
            float4 v = {0.f, 0.f, 0.f, 0.f};
            if (kg < 273) v = *(const float4*)(ew1 + (size_t)kg * 128 + c);
            *(float4*)&Bs[kk][c] = v;
        }
        __syncthreads();
        #pragma unroll 8
        for (int kk = 0; kk < 32; kk++) {
            float4 a  = *(const float4*)&At[kb * 32 + kk][ty * 4];
            float4 b0 = *(const float4*)&Bs[kk][tx * 8];
            float4 b1 = *(const float4*)&Bs[kk][tx * 8 + 4];
            float av[4] = {a.x, a.y, a.z, a.w};
            float bv[8] = {b0.x, b0.y, b0.z, b0.w, b1.x, b1.y, b1.z, b1.w};
            #pragma unroll
            for (int i = 0; i < 4; i++)
                #pragma unroll
                for (int j = 0; j < 8; j++)
                    acc[i][j] = fmaf(av[i], bv[j], acc[i][j]);
        }
    }
    __syncthreads();
    #pragma unroll
    for (int i = 0; i < 4; i++)
        #pragma unroll
        for (int j = 0; j < 8; j++) {
            float v = silu_f(acc[i][j] + eb1[tx*8+j]);
            At[tx*8+j][ty*4+i] = v;      // m1^T
        }

    // ---- phase 2: m = silu(m1 @ ew2 + eb2), K=128 ----
    #pragma unroll
    for (int i = 0; i < 4; i++)
        #pragma unroll
        for (int j = 0; j < 8; j++) acc[i][j] = 0.f;

    for (int kb = 0; kb < 4; kb++) {
        __syncthreads();
        #pragma unroll
        for (int j = 0; j < 8; j++) {
            int li = j * 512 + tid * 4;
            int kk = li >> 7, c = li & 127;
            float4 v = *(const float4*)(ew2 + (size_t)(kb * 32 + kk) * 128 + c);
            *(float4*)&Bs[kk][c] = v;
        }
        __syncthreads();
        #pragma unroll 8
        for (int kk = 0; kk < 32; kk++) {
            float4 a  = *(const float4*)&At[kb * 32 + kk][ty * 4];
            float4 b0 = *(const float4*)&Bs[kk][tx * 8];
            float4 b1 = *(const float4*)&Bs[kk][tx * 8 + 4];
            float av[4] = {a.x, a.y, a.z, a.w};
            float bv[8] = {b0.x, b0.y, b0.z, b0.w, b1.x, b1.y, b1.z, b1.w};
            #pragma unroll
            for (int i = 0; i < 4; i++)
                #pragma unroll
                for (int j = 0; j < 8; j++)
                    acc[i][j] = fmaf(av[i], bv[j], acc[i][j]);
        }
    }
    __syncthreads();
    float mval[4][8];
    #pragma unroll
    for (int i = 0; i < 4; i++)
        #pragma unroll
        for (int j = 0; j < 8; j++) {
            float v = silu_f(acc[i][j] + eb2[tx*8+j]);
            mval[i][j] = v;
            At[128 + tx*8+j][ty*4+i] = v;   // m^T
        }

    // ---- phase 3: w = silu(m @ cw1 + cb1) @ cw2 ----
    #pragma unroll
    for (int i = 0; i < 4; i++)
        #pragma unroll
        for (int j = 0; j < 8; j++) acc[i][j] = 0.f;

    for (int kb = 0; kb < 4; kb++) {
        __syncthreads();
        #pragma unroll
        for (int j = 0; j < 8; j++) {
            int li = j * 512 + tid * 4;
            int kk = li >> 7, c = li & 127;
            float4 v = *(const float4*)(cw1 + (size_t)(kb * 32 + kk) * 128 + c);
            *(float4*)&Bs[kk][c] = v;
        }
        __syncthreads();
        #pragma unroll 8
        for (int kk = 0; kk < 32; kk++) {
            float4 a  = *(const float4*)&At[128 + kb * 32 + kk][ty * 4];
            float4 b0 = *(const float4*)&Bs[kk][tx * 8];
            float4 b1 = *(const float4*)&Bs[kk][tx * 8 + 4];
            float av[4] = {a.x, a.y, a.z, a.w};
            float bv[8] = {b0.x, b0.y, b0.z, b0.w, b1.x, b1.y, b1.z, b1.w};
            #pragma unroll
            for (int i = 0; i < 4; i++)
                #pragma unroll
                for (int j = 0; j < 8; j++)
                    acc[i][j] = fmaf(av[i], bv[j], acc[i][j]);
        }
    }
    float cw[8];
    *(float4*)&cw[0] = *(const float4*)(cw2 + tx * 8);
    *(float4*)&cw[4] = *(const float4*)(cw2 + tx * 8 + 4);
    #pragma unroll
    for (int i = 0; i < 4; i++) {
        float p = 0.f;
        #pragma unroll
        for (int j = 0; j < 8; j++) {
            float v = silu_f(acc[i][j] + cb1[tx*8+j]);
            p = fmaf(v, cw[j], p);
        }
        red[ty*4+i][tx] = p;
    }
    __syncthreads();

    // ---- scatter ----
    if (tid < 32) {
        float s = 0.f;
        #pragma unroll
        for (int q = 0; q < 16; q++) s += red[tid][q];
        int ra = rowS[tid];
        #pragma unroll
        for (int k = 0; k < 3; k++)
            atomicAdd(&xacc[ra*3+k], diffS[tid][k] * s);
    }
    #pragma unroll
    for (int i = 0; i < 4; i++) {
        int ra = rowS[ty*4+i];
        #pragma unroll
        for (int j = 0; j < 8; j++)
            atomicAdd(&agg[(size_t)ra*128 + tx*8+j], mval[i][j]);
    }
}

// ---------------- coordinate update ----------------

__global__ void k_xupd(const float* __restrict__ xcur, const float* __restrict__ xacc,
                       const int* __restrict__ degB, float* __restrict__ xnext) {
    int i = blockIdx.x * 256 + threadIdx.x;
    if (i < NATOM * 3) {
        int a = i / 3;
        float cnt = fmaxf(3.0f * (float)degB[a >> 2], 1.0f);
        xnext[i] = xcur[i] + xacc[i] / cnt;
    }
}

// ---------------- launch ----------------

extern "C" void kernel_launch(void* const* d_in, const int* in_sizes, int n_in,
                              void* d_out, int out_size, void* d_ws, size_t ws_size,
                              hipStream_t stream) {
    const float* H        = (const float*)d_in[0];
    const float* Z        = (const float*)d_in[1];
    const int*   edges    = (const int*)  d_in[4];
    const float* eattr    = (const float*)d_in[5];
    const float* emb_in_w = (const float*)d_in[6];
    const float* emb_in_b = (const float*)d_in[7];
    const float* emb_out_w= (const float*)d_in[8];
    const float* emb_out_b= (const float*)d_in[9];
    const float* edge_w1  = (const float*)d_in[10];
    const float* edge_b1  = (const float*)d_in[11];
    const float* edge_w2  = (const float*)d_in[12];
    const float* edge_b2  = (const float*)d_in[13];
    const float* node_w1  = (const float*)d_in[14];
    const float* node_b1  = (const float*)d_in[15];
    const float* node_w2  = (const float*)d_in[16];
    const float* node_b2  = (const float*)d_in[17];
    const float* coord_w1 = (const float*)d_in[18];
    const float* coord_b1 = (const float*)d_in[19];
    const float* coord_w2 = (const float*)d_in[20];

    float* out  = (float*)d_out;
    float* hbuf = out;                              // [N][128]
    float* xout = out + (size_t)NATOM * 128;        // [N][3]

    // workspace (~45.4 MB)
    char* w = (char*)d_ws;
    float* agg  = (float*)w;  w += (size_t)NATOM * 128 * 4;   // 40.96 MB (also node hidden, in-place)
    float* xacc = (float*)w;  w += (size_t)NATOM * 3 * 4;
    float* xA   = (float*)w;  w += (size_t)NATOM * 3 * 4;
    float* xB   = (float*)w;  w += (size_t)NATOM * 3 * 4;
    int* colIdx = (int*)w;    w += (size_t)EALL * 4;
    int* degB   = (int*)w;    w += (size_t)NBLK * 4;

    hipMemsetAsync(degB, 0, NBLK * sizeof(int), stream);
    k_count<<<(EBK + 255) / 256, 256, 0, stream>>>(edges, degB);
    k_topk <<<(EBK * UU + 255) / 256, 256, 0, stream>>>(edges, Z, colIdx);

    // h = H @ emb_in_w + b
    k_gemm<128, false, false, false><<<NATOM / 32, 128, 0, stream>>>(
        H, nullptr, emb_in_w, emb_in_b, nullptr, hbuf, NATOM);

    const float* xcur = Z;
    for (int l = 0; l < LAY; l++) {
        float* xnext = (l == 0) ? xA : (l == 1) ? xB : xout;

        hipMemsetAsync(agg,  0, (size_t)NATOM * 128 * sizeof(float), stream);
        hipMemsetAsync(xacc, 0, (size_t)NATOM * 3   * sizeof(float), stream);

        k_edge_fused<<<EALL / 32, 128, 0, stream>>>(
            hbuf, xcur, eattr, edges, colIdx,
            edge_w1 + (size_t)l * 273 * 128, edge_b1 + l * 128,
            edge_w2 + (size_t)l * 128 * 128, edge_b2 + l * 128,
            coord_w1 + (size_t)l * 128 * 128, coord_b1 + l * 128,
            coord_w2 + (size_t)l * 128,
            agg, xacc);

        k_xupd<<<(NATOM * 3 + 255) / 256, 256, 0, stream>>>(xcur, xacc, degB, xnext);

        // node MLP: hidden = silu([h|agg] @ w1 + b1)  (in-place into agg)
        k_gemm<256, true, false, true><<<NATOM / 32, 128, 0, stream>>>(
            hbuf, agg, node_w1 + (size_t)l * 256 * 128, node_b1 + l * 128,
            nullptr, agg, NATOM);
        // h += hidden @ w2 + b2
        k_gemm<128, false, true, false><<<NATOM / 32, 128, 0, stream>>>(
            agg, nullptr, node_w2 + (size_t)l * 128 * 128, node_b2 + l * 128,
            hbuf, hbuf, NATOM);

        xcur = xnext;
    }

    k_gemm<128, false, false, false><<<NATOM / 32, 128, 0, stream>>>(
        hbuf, nullptr, emb_out_w, emb_out_b, nullptr, hbuf, NATOM);
}